// Round 6
// baseline (97.457 us; speedup 1.0000x reference)
//
#include <hip/hip_runtime.h>
#include <hip/hip_bf16.h>
#include <stdint.h>

typedef __bf16 bf16;
typedef __bf16 bf16x8 __attribute__((ext_vector_type(8)));
typedef __bf16 bf16x4 __attribute__((ext_vector_type(4)));
typedef float f32x4 __attribute__((ext_vector_type(4)));

template <int V> struct Int { static constexpr int value = V; };

// async global->LDS, 16B per lane. LDS dest must be linear in lane order.
static __device__ __forceinline__ void gl2lds16(const void* g, void* l) {
  const __attribute__((address_space(1))) void* gp =
      reinterpret_cast<const __attribute__((address_space(1))) void*>(
          reinterpret_cast<uintptr_t>(g));
  __attribute__((address_space(3))) void* lp =
      reinterpret_cast<__attribute__((address_space(3))) void*>(
          static_cast<uint32_t>(reinterpret_cast<uintptr_t>(l)));
  __builtin_amdgcn_global_load_lds(gp, lp, 16, 0, 0);
}

__global__ __launch_bounds__(256) void cvt_f32_bf16(const float* __restrict__ src,
                                                    bf16* __restrict__ dst, int n4) {
  int i = blockIdx.x * blockDim.x + threadIdx.x;
  const int stride = gridDim.x * blockDim.x;
  for (; i < n4; i += stride) {
    const float4 v = reinterpret_cast<const float4*>(src)[i];
    bf16x4 o;
    o[0] = (bf16)v.x; o[1] = (bf16)v.y; o[2] = (bf16)v.z; o[3] = (bf16)v.w;
    reinterpret_cast<bf16x4*>(dst)[i] = o;
  }
}

// C[m][e] = sum_k X[m][k] * W[e][k];  M=8192, N=1536, K=512.  128x128 tile, BK=32.
// 4 waves, each owns 64x64 (4x4 frags of 16x16x32). Epilogue scatters Q/K/V^T.
__global__ __launch_bounds__(256) void qkv_gemm(const bf16* __restrict__ X,
                                                const bf16* __restrict__ W,
                                                bf16* __restrict__ Qb,
                                                bf16* __restrict__ Kb,
                                                bf16* __restrict__ Vt) {
  __shared__ __align__(16) bf16 AshX[8192];  // [2][128*32]
  __shared__ __align__(16) bf16 BshX[8192];
  const int t = threadIdx.x;
  const int lane = t & 63;
  const int w = t >> 6;
  const int fr = lane & 15, fg = lane >> 4;
  const int wr = w >> 1, wc = w & 1;
  const int m0 = blockIdx.x * 128;
  const int n0 = blockIdx.y * 128;
  // staging: chunk t -> row t>>2, seg t&3 -> LDS elem t*8; chunk t+256 -> +2048
  const int r0 = t >> 2, seg = t & 3;
  const bf16* pA0 = X + (m0 + r0) * 512 + seg * 8;
  const bf16* pA1 = X + (m0 + r0 + 64) * 512 + seg * 8;
  const bf16* pB0 = W + (n0 + r0) * 512 + seg * 8;
  const bf16* pB1 = W + (n0 + r0 + 64) * 512 + seg * 8;
  const bf16* ap = AshX + (wr * 64 + fr) * 32 + fg * 8;
  const bf16* bp = BshX + (wc * 64 + fr) * 32 + fg * 8;

  f32x4 acc[4][4] = {};

  auto stage = [&](auto Bt) {
    constexpr int B = decltype(Bt)::value;
    gl2lds16(pA0, (void*)(AshX + B * 4096 + t * 8));
    gl2lds16(pA1, (void*)(AshX + B * 4096 + 2048 + t * 8));
    gl2lds16(pB0, (void*)(BshX + B * 4096 + t * 8));
    gl2lds16(pB1, (void*)(BshX + B * 4096 + 2048 + t * 8));
    pA0 += 32; pA1 += 32; pB0 += 32; pB1 += 32;
  };
  auto step = [&](auto Bt) {
    constexpr int B = decltype(Bt)::value;
    bf16x8 a[4], b[4];
#pragma unroll
    for (int m = 0; m < 4; ++m) a[m] = *reinterpret_cast<const bf16x8*>(ap + B * 4096 + m * 512);
#pragma unroll
    for (int n = 0; n < 4; ++n) b[n] = *reinterpret_cast<const bf16x8*>(bp + B * 4096 + n * 512);
#pragma unroll
    for (int m = 0; m < 4; ++m)
#pragma unroll
      for (int n = 0; n < 4; ++n)
        acc[m][n] = __builtin_amdgcn_mfma_f32_16x16x32_bf16(a[m], b[n], acc[m][n], 0, 0, 0);
  };

  stage(Int<0>{});
  __syncthreads();
  for (int kt = 0; kt < 16; kt += 2) {
    stage(Int<1>{});
    step(Int<0>{});
    __syncthreads();
    if (kt < 14) stage(Int<0>{});
    step(Int<1>{});
    __syncthreads();
  }

  // epilogue. C/D: col = lane&15 -> e = n0+wc*64+16n+fr; row = m0+wr*64+16m+fg*4+r
  const int which = n0 >> 9;  // 0=Q 1=K 2=V (uniform per block)
#pragma unroll
  for (int n = 0; n < 4; ++n) {
    const int e = n0 + wc * 64 + 16 * n + fr;
    const int h = (e >> 6) & 7;
    const int d = e & 63;
#pragma unroll
    for (int m = 0; m < 4; ++m) {
      const int mbase = m0 + wr * 64 + 16 * m + fg * 4;
      if (which == 2) {
        bf16x4 pk;
#pragma unroll
        for (int r = 0; r < 4; ++r) pk[r] = (bf16)acc[m][n][r];
        const int b = mbase >> 11, tok = mbase & 2047;
        *reinterpret_cast<bf16x4*>(&Vt[((b * 8 + h) * 64 + d) * 2048 + tok]) = pk;
      } else {
        bf16* dst = (which == 0) ? Qb : Kb;
        const float sc = (which == 0) ? (0.125f * 1.44269504088896f) : 1.0f;
#pragma unroll
        for (int r = 0; r < 4; ++r) {
          const int row = mbase + r;
          const int b = row >> 11, tok = row & 2047;
          dst[((b * 8 + h) * 2048 + tok) * 64 + d] = (bf16)(acc[m][n][r] * sc);
        }
      }
    }
  }
}

// Flash attention, swapped-operand, no-max exp2 softmax, q=16 per wave.
// Q [BH][2048][64] (prescaled by 0.125*log2e), K [BH][2048][64], V^T [BH][64][2048].
// Block: 4 waves x 16 q-rows = 64 q. Grid (32 bh, 32) = 1024 blocks -> 4 blocks/CU,
// 16 waves/CU (4/SIMD). Lane owns one q row (q = q0 + fr).
// K rows PERMUTED at staging so S^T lands in PV B-frag layout (see r3 header).
// LDS arena: K0 @0 | K1 @8192 | V0 @16384 | V1 @24576 (bytes), XOR-swizzled rows.
__global__ __launch_bounds__(256, 4) void attn_fwd(const bf16* __restrict__ Qb,
                                                   const bf16* __restrict__ Kb,
                                                   const bf16* __restrict__ Vt,
                                                   bf16* __restrict__ Ob) {
  __shared__ __align__(16) bf16 sh[16384];
  const int t = threadIdx.x;
  const int lane = t & 63;
  const int w = t >> 6;
  const int fr = lane & 15, fg = lane >> 4;
  const int bh = blockIdx.x;
  const int q0 = blockIdx.y * 64 + 16 * w;

  // Q fragment (B-operand): col=q=q0+fr, k = 8*fg + i
  const bf16* Qrow = Qb + (bh * 2048 + q0 + fr) * 64;
  const bf16x8 qf0 = *reinterpret_cast<const bf16x8*>(Qrow + fg * 8);
  const bf16x8 qf1 = *reinterpret_cast<const bf16x8*>(Qrow + 32 + fg * 8);

  bf16x8 ones;
#pragma unroll
  for (int i = 0; i < 8; ++i) ones[i] = (bf16)1.0f;

  // staging: chunk c: LDS row=c>>3, seg=c&7; src seg ^= (dstrow&7); K row-permuted.
  const int c0row = t >> 3, cseg = t & 7;
  const int c1row = c0row + 32;
  const int s0 = (cseg ^ (c0row & 7)) * 8;
  const int s1 = (cseg ^ (c1row & 7)) * 8;
  const int kp0 = 32 * ((c0row >> 4) >> 1) + 8 * ((c0row & 15) >> 2) +
                  4 * ((c0row >> 4) & 1) + (c0row & 3);
  const int kp1 = 32 * ((c1row >> 4) >> 1) + 8 * ((c1row & 15) >> 2) +
                  4 * ((c1row >> 4) & 1) + (c1row & 3);
  const bf16* pK0 = Kb + bh * 131072 + kp0 * 64 + s0;
  const bf16* pK1 = Kb + bh * 131072 + kp1 * 64 + s1;
  const bf16* pV0 = Vt + bh * 131072 + c0row * 2048 + s0;
  const bf16* pV1 = Vt + bh * 131072 + c1row * 2048 + s1;

  // LDS read byte offsets (2 VGPRs; everything else is an immediate)
  const int swz = (fr & 7) << 4;
  const int ko0 = fr * 128 + ((fg * 16) ^ swz);
  const int ko1 = fr * 128 + ((64 + fg * 16) ^ swz);
  const char* shb = reinterpret_cast<const char*>(sh);

  f32x4 oacc[4] = {};
  f32x4 lacc = {};

  auto stage = [&](auto Bt) {
    constexpr int B = decltype(Bt)::value;
    gl2lds16(pK0, (void*)(sh + B * 4096 + t * 8));
    gl2lds16(pK1, (void*)(sh + B * 4096 + 2048 + t * 8));
    gl2lds16(pV0, (void*)(sh + 8192 + B * 4096 + t * 8));
    gl2lds16(pV1, (void*)(sh + 8192 + B * 4096 + 2048 + t * 8));
    pK0 += 4096; pK1 += 4096; pV0 += 64; pV1 += 64;
  };

  auto compute = [&](auto Bt) {
    constexpr int B = decltype(Bt)::value;
    f32x4 s[4] = {};
#pragma unroll
    for (int j = 0; j < 4; ++j) {
      const bf16x8 kf0 = *reinterpret_cast<const bf16x8*>(shb + ko0 + (B * 8192 + j * 2048));
      s[j] = __builtin_amdgcn_mfma_f32_16x16x32_bf16(kf0, qf0, s[j], 0, 0, 0);
      const bf16x8 kf1 = *reinterpret_cast<const bf16x8*>(shb + ko1 + (B * 8192 + j * 2048));
      s[j] = __builtin_amdgcn_mfma_f32_16x16x32_bf16(kf1, qf1, s[j], 0, 0, 0);
    }
    bf16x8 pf[2];
#pragma unroll
    for (int j = 0; j < 4; ++j)
#pragma unroll
      for (int r = 0; r < 4; ++r) {
        pf[j >> 1][4 * (j & 1) + r] = (bf16)exp2f(s[j][r]);
      }
    __builtin_amdgcn_s_setprio(1);
#pragma unroll
    for (int ss = 0; ss < 2; ++ss) {
      lacc = __builtin_amdgcn_mfma_f32_16x16x32_bf16(ones, pf[ss], lacc, 0, 0, 0);
#pragma unroll
      for (int j = 0; j < 4; ++j) {
        const bf16x8 vf = *reinterpret_cast<const bf16x8*>(
            shb + (ss ? ko1 : ko0) + (16384 + B * 8192 + j * 2048));
        oacc[j] = __builtin_amdgcn_mfma_f32_16x16x32_bf16(vf, pf[ss], oacc[j], 0, 0, 0);
      }
    }
    __builtin_amdgcn_s_setprio(0);
  };

  stage(Int<0>{});
  __syncthreads();
  for (int kt = 0; kt < 32; kt += 2) {
    stage(Int<1>{});
    compute(Int<0>{});
    __syncthreads();
    if (kt < 30) stage(Int<0>{});
    compute(Int<1>{});
    __syncthreads();
  }

  // epilogue: oacc[j][r] = O[q][d=16j+4fg+r]; l = lacc[0] (all slots equal)
  const int b = bh >> 3, h = bh & 7;
  const int q = q0 + fr;
  const float inv = 1.0f / lacc[0];
#pragma unroll
  for (int j = 0; j < 4; ++j) {
    bf16x4 o4;
#pragma unroll
    for (int r = 0; r < 4; ++r) o4[r] = (bf16)(oacc[j][r] * inv);
    *reinterpret_cast<bf16x4*>(&Ob[(b * 2048 + q) * 512 + h * 64 + 16 * j + 4 * fg]) = o4;
  }
}

// Y[m][n] = sum_k O[m][k]*W[n][k] + bias[n];  M=8192, N=512, K=512. fp32 out.
// 128x64 tile, BK=32; 4 waves each own 64x32 (4x2 frags). Grid 512 = 2 blocks/CU.
__global__ __launch_bounds__(256) void out_gemm(const bf16* __restrict__ O,
                                                const bf16* __restrict__ W,
                                                const float* __restrict__ bias,
                                                float* __restrict__ Y) {
  __shared__ __align__(16) bf16 Ash[8192];  // [2][128*32]
  __shared__ __align__(16) bf16 Bsh[4096];  // [2][64*32]
  const int t = threadIdx.x;
  const int lane = t & 63;
  const int w = t >> 6;
  const int fr = lane & 15, fg = lane >> 4;
  const int wr = w >> 1, wc = w & 1;
  const int m0 = blockIdx.x * 128;
  const int n0 = blockIdx.y * 64;
  const int r0 = t >> 2, seg = t & 3;
  const bf16* pA0 = O + (m0 + r0) * 512 + seg * 8;
  const bf16* pA1 = O + (m0 + r0 + 64) * 512 + seg * 8;
  const bf16* pB0 = W + (n0 + r0) * 512 + seg * 8;
  const bf16* ap = Ash + (wr * 64 + fr) * 32 + fg * 8;
  const bf16* bp = Bsh + (wc * 32 + fr) * 32 + fg * 8;

  f32x4 acc[4][2] = {};

  auto stage = [&](auto Bt) {
    constexpr int B = decltype(Bt)::value;
    gl2lds16(pA0, (void*)(Ash + B * 4096 + t * 8));
    gl2lds16(pA1, (void*)(Ash + B * 4096 + 2048 + t * 8));
    gl2lds16(pB0, (void*)(Bsh + B * 2048 + t * 8));
    pA0 += 32; pA1 += 32; pB0 += 32;
  };
  auto step = [&](auto Bt) {
    constexpr int B = decltype(Bt)::value;
    bf16x8 a[4], b[2];
#pragma unroll
    for (int m = 0; m < 4; ++m) a[m] = *reinterpret_cast<const bf16x8*>(ap + B * 4096 + m * 512);
#pragma unroll
    for (int n = 0; n < 2; ++n) b[n] = *reinterpret_cast<const bf16x8*>(bp + B * 2048 + n * 512);
#pragma unroll
    for (int m = 0; m < 4; ++m)
#pragma unroll
      for (int n = 0; n < 2; ++n)
        acc[m][n] = __builtin_amdgcn_mfma_f32_16x16x32_bf16(a[m], b[n], acc[m][n], 0, 0, 0);
  };

  stage(Int<0>{});
  __syncthreads();
  for (int kt = 0; kt < 16; kt += 2) {
    stage(Int<1>{});
    step(Int<0>{});
    __syncthreads();
    if (kt < 14) stage(Int<0>{});
    step(Int<1>{});
    __syncthreads();
  }

#pragma unroll
  for (int n = 0; n < 2; ++n) {
    const int col = n0 + wc * 32 + 16 * n + fr;
    const float bv = bias[col];
#pragma unroll
    for (int m = 0; m < 4; ++m) {
      const int mbase = m0 + wr * 64 + 16 * m + fg * 4;
#pragma unroll
      for (int r = 0; r < 4; ++r) {
        Y[(mbase + r) * 512 + col] = acc[m][n][r] + bv;
      }
    }
  }
}

extern "C" void kernel_launch(void* const* d_in, const int* in_sizes, int n_in,
                              void* d_out, int out_size, void* d_ws, size_t ws_size,
                              hipStream_t stream) {
  const float* x = (const float*)d_in[0];      // [4,2048,512]
  const float* w_qkv = (const float*)d_in[1];  // [1536,512]
  const float* w_out = (const float*)d_in[2];  // [512,512]
  const float* b_out = (const float*)d_in[3];  // [512]
  float* y = (float*)d_out;                    // [4,2048,512] fp32
  char* ws = (char*)d_ws;
  bf16* xb    = (bf16*)(ws);             // 8 MB
  bf16* wqkvb = (bf16*)(ws + 8388608);   // 1.5 MB
  bf16* woutb = (bf16*)(ws + 9961472);   // 0.5 MB
  bf16* Qb    = (bf16*)(ws + 10485760);  // 8 MB  [BH][N][64], prescaled
  bf16* Kb    = (bf16*)(ws + 18874368);  // 8 MB  [BH][N][64]
  bf16* Vt    = (bf16*)(ws + 27262976);  // 8 MB  [BH][64][N]
  bf16* Ob    = (bf16*)(ws + 35651584);  // 8 MB  [B][N][512]

  hipLaunchKernelGGL(cvt_f32_bf16, dim3(2048), dim3(256), 0, stream, x, xb, 4194304 / 4);
  hipLaunchKernelGGL(cvt_f32_bf16, dim3(768), dim3(256), 0, stream, w_qkv, wqkvb, 786432 / 4);
  hipLaunchKernelGGL(cvt_f32_bf16, dim3(256), dim3(256), 0, stream, w_out, woutb, 262144 / 4);
  hipLaunchKernelGGL(qkv_gemm, dim3(64, 12), dim3(256), 0, stream, xb, wqkvb, Qb, Kb, Vt);
  hipLaunchKernelGGL(attn_fwd, dim3(32, 32), dim3(256), 0, stream, Qb, Kb, Vt, Ob);
  hipLaunchKernelGGL(out_gemm, dim3(64, 8), dim3(256), 0, stream, Ob, woutb, b_out, y);
}

// Round 7
// 86.940 us; speedup vs baseline: 1.1210x; 1.1210x over previous
//
#include <hip/hip_runtime.h>
#include <hip/hip_bf16.h>
#include <stdint.h>

typedef __bf16 bf16;
typedef __bf16 bf16x8 __attribute__((ext_vector_type(8)));
typedef __bf16 bf16x4 __attribute__((ext_vector_type(4)));
typedef float f32x4 __attribute__((ext_vector_type(4)));

template <int V> struct Int { static constexpr int value = V; };

// async global->LDS, 16B per lane. LDS dest must be linear in lane order.
static __device__ __forceinline__ void gl2lds16(const void* g, void* l) {
  const __attribute__((address_space(1))) void* gp =
      reinterpret_cast<const __attribute__((address_space(1))) void*>(
          reinterpret_cast<uintptr_t>(g));
  __attribute__((address_space(3))) void* lp =
      reinterpret_cast<__attribute__((address_space(3))) void*>(
          static_cast<uint32_t>(reinterpret_cast<uintptr_t>(l)));
  __builtin_amdgcn_global_load_lds(gp, lp, 16, 0, 0);
}

// bare v_exp_f32 through the compiler intrinsic (hazard-safe, unlike inline asm).
static __device__ __forceinline__ float fast_exp2(float x) {
#if __has_builtin(__builtin_amdgcn_exp2f)
  return __builtin_amdgcn_exp2f(x);
#else
  return exp2f(x);
#endif
}

__global__ __launch_bounds__(256) void cvt_f32_bf16(const float* __restrict__ src,
                                                    bf16* __restrict__ dst, int n4) {
  int i = blockIdx.x * blockDim.x + threadIdx.x;
  const int stride = gridDim.x * blockDim.x;
  for (; i < n4; i += stride) {
    const float4 v = reinterpret_cast<const float4*>(src)[i];
    bf16x4 o;
    o[0] = (bf16)v.x; o[1] = (bf16)v.y; o[2] = (bf16)v.z; o[3] = (bf16)v.w;
    reinterpret_cast<bf16x4*>(dst)[i] = o;
  }
}

// C[m][e] = sum_k X[m][k] * W[e][k];  M=8192, N=1536, K=512.  128x128 tile, BK=32.
// 4 waves, each owns 64x64 (4x4 frags of 16x16x32). Epilogue scatters Q/K/V^T.
__global__ __launch_bounds__(256) void qkv_gemm(const bf16* __restrict__ X,
                                                const bf16* __restrict__ W,
                                                bf16* __restrict__ Qb,
                                                bf16* __restrict__ Kb,
                                                bf16* __restrict__ Vt) {
  __shared__ __align__(16) bf16 AshX[8192];  // [2][128*32]
  __shared__ __align__(16) bf16 BshX[8192];
  const int t = threadIdx.x;
  const int lane = t & 63;
  const int w = t >> 6;
  const int fr = lane & 15, fg = lane >> 4;
  const int wr = w >> 1, wc = w & 1;
  const int m0 = blockIdx.x * 128;
  const int n0 = blockIdx.y * 128;
  // staging: chunk t -> row t>>2, seg t&3 -> LDS elem t*8; chunk t+256 -> +2048
  const int r0 = t >> 2, seg = t & 3;
  const bf16* pA0 = X + (m0 + r0) * 512 + seg * 8;
  const bf16* pA1 = X + (m0 + r0 + 64) * 512 + seg * 8;
  const bf16* pB0 = W + (n0 + r0) * 512 + seg * 8;
  const bf16* pB1 = W + (n0 + r0 + 64) * 512 + seg * 8;
  const bf16* ap = AshX + (wr * 64 + fr) * 32 + fg * 8;
  const bf16* bp = BshX + (wc * 64 + fr) * 32 + fg * 8;

  f32x4 acc[4][4] = {};

  auto stage = [&](auto Bt) {
    constexpr int B = decltype(Bt)::value;
    gl2lds16(pA0, (void*)(AshX + B * 4096 + t * 8));
    gl2lds16(pA1, (void*)(AshX + B * 4096 + 2048 + t * 8));
    gl2lds16(pB0, (void*)(BshX + B * 4096 + t * 8));
    gl2lds16(pB1, (void*)(BshX + B * 4096 + 2048 + t * 8));
    pA0 += 32; pA1 += 32; pB0 += 32; pB1 += 32;
  };
  auto step = [&](auto Bt) {
    constexpr int B = decltype(Bt)::value;
    bf16x8 a[4], b[4];
#pragma unroll
    for (int m = 0; m < 4; ++m) a[m] = *reinterpret_cast<const bf16x8*>(ap + B * 4096 + m * 512);
#pragma unroll
    for (int n = 0; n < 4; ++n) b[n] = *reinterpret_cast<const bf16x8*>(bp + B * 4096 + n * 512);
#pragma unroll
    for (int m = 0; m < 4; ++m)
#pragma unroll
      for (int n = 0; n < 4; ++n)
        acc[m][n] = __builtin_amdgcn_mfma_f32_16x16x32_bf16(a[m], b[n], acc[m][n], 0, 0, 0);
  };

  stage(Int<0>{});
  __syncthreads();
  for (int kt = 0; kt < 16; kt += 2) {
    stage(Int<1>{});
    step(Int<0>{});
    __syncthreads();
    if (kt < 14) stage(Int<0>{});
    step(Int<1>{});
    __syncthreads();
  }

  // epilogue. C/D: col = lane&15 -> e = n0+wc*64+16n+fr; row = m0+wr*64+16m+fg*4+r
  const int which = n0 >> 9;  // 0=Q 1=K 2=V (uniform per block)
#pragma unroll
  for (int n = 0; n < 4; ++n) {
    const int e = n0 + wc * 64 + 16 * n + fr;
    const int h = (e >> 6) & 7;
    const int d = e & 63;
#pragma unroll
    for (int m = 0; m < 4; ++m) {
      const int mbase = m0 + wr * 64 + 16 * m + fg * 4;
      if (which == 2) {
        bf16x4 pk;
#pragma unroll
        for (int r = 0; r < 4; ++r) pk[r] = (bf16)acc[m][n][r];
        const int b = mbase >> 11, tok = mbase & 2047;
        *reinterpret_cast<bf16x4*>(&Vt[((b * 8 + h) * 64 + d) * 2048 + tok]) = pk;
      } else {
        bf16* dst = (which == 0) ? Qb : Kb;
        const float sc = (which == 0) ? (0.125f * 1.44269504088896f) : 1.0f;
#pragma unroll
        for (int r = 0; r < 4; ++r) {
          const int row = mbase + r;
          const int b = row >> 11, tok = row & 2047;
          dst[((b * 8 + h) * 2048 + tok) * 64 + d] = (bf16)(acc[m][n][r] * sc);
        }
      }
    }
  }
}

// Flash attention, swapped-operand, no-max exp2 softmax, q=16 per wave.
// Q [BH][2048][64] (prescaled by 0.125*log2e), K [BH][2048][64], V^T [BH][64][2048].
// Block: 4 waves x 16 q-rows = 64 q. Grid (32 bh, 32) = 1024 blocks -> 4 blocks/CU,
// 16 waves/CU (4/SIMD). Lane owns one q row (q = q0 + fr).
// K rows PERMUTED at staging so S^T lands in PV B-frag layout (see r3 header).
// LDS arena: K0 @0 | K1 @8192 | V0 @16384 | V1 @24576 (bytes), XOR-swizzled rows.
__global__ __launch_bounds__(256, 4) void attn_fwd(const bf16* __restrict__ Qb,
                                                   const bf16* __restrict__ Kb,
                                                   const bf16* __restrict__ Vt,
                                                   bf16* __restrict__ Ob) {
  __shared__ __align__(16) bf16 sh[16384];
  const int t = threadIdx.x;
  const int lane = t & 63;
  const int w = t >> 6;
  const int fr = lane & 15, fg = lane >> 4;
  const int bh = blockIdx.x;
  const int q0 = blockIdx.y * 64 + 16 * w;

  // Q fragment (B-operand): col=q=q0+fr, k = 8*fg + i
  const bf16* Qrow = Qb + (bh * 2048 + q0 + fr) * 64;
  const bf16x8 qf0 = *reinterpret_cast<const bf16x8*>(Qrow + fg * 8);
  const bf16x8 qf1 = *reinterpret_cast<const bf16x8*>(Qrow + 32 + fg * 8);

  bf16x8 ones;
#pragma unroll
  for (int i = 0; i < 8; ++i) ones[i] = (bf16)1.0f;

  // staging: chunk c: LDS row=c>>3, seg=c&7; src seg ^= (dstrow&7); K row-permuted.
  const int c0row = t >> 3, cseg = t & 7;
  const int c1row = c0row + 32;
  const int s0 = (cseg ^ (c0row & 7)) * 8;
  const int s1 = (cseg ^ (c1row & 7)) * 8;
  const int kp0 = 32 * ((c0row >> 4) >> 1) + 8 * ((c0row & 15) >> 2) +
                  4 * ((c0row >> 4) & 1) + (c0row & 3);
  const int kp1 = 32 * ((c1row >> 4) >> 1) + 8 * ((c1row & 15) >> 2) +
                  4 * ((c1row >> 4) & 1) + (c1row & 3);
  const bf16* pK0 = Kb + bh * 131072 + kp0 * 64 + s0;
  const bf16* pK1 = Kb + bh * 131072 + kp1 * 64 + s1;
  const bf16* pV0 = Vt + bh * 131072 + c0row * 2048 + s0;
  const bf16* pV1 = Vt + bh * 131072 + c1row * 2048 + s1;

  // LDS read byte offsets (2 VGPRs; everything else is an immediate)
  const int swz = (fr & 7) << 4;
  const int ko0 = fr * 128 + ((fg * 16) ^ swz);
  const int ko1 = fr * 128 + ((64 + fg * 16) ^ swz);
  const char* shb = reinterpret_cast<const char*>(sh);

  f32x4 oacc[4] = {};
  f32x4 lacc = {};

  auto stage = [&](auto Bt) {
    constexpr int B = decltype(Bt)::value;
    gl2lds16(pK0, (void*)(sh + B * 4096 + t * 8));
    gl2lds16(pK1, (void*)(sh + B * 4096 + 2048 + t * 8));
    gl2lds16(pV0, (void*)(sh + 8192 + B * 4096 + t * 8));
    gl2lds16(pV1, (void*)(sh + 8192 + B * 4096 + 2048 + t * 8));
    pK0 += 4096; pK1 += 4096; pV0 += 64; pV1 += 64;
  };

  auto compute = [&](auto Bt) {
    constexpr int B = decltype(Bt)::value;
    f32x4 s[4] = {};
#pragma unroll
    for (int j = 0; j < 4; ++j) {
      const bf16x8 kf0 = *reinterpret_cast<const bf16x8*>(shb + ko0 + (B * 8192 + j * 2048));
      s[j] = __builtin_amdgcn_mfma_f32_16x16x32_bf16(kf0, qf0, s[j], 0, 0, 0);
      const bf16x8 kf1 = *reinterpret_cast<const bf16x8*>(shb + ko1 + (B * 8192 + j * 2048));
      s[j] = __builtin_amdgcn_mfma_f32_16x16x32_bf16(kf1, qf1, s[j], 0, 0, 0);
    }
    bf16x8 pf[2];
#pragma unroll
    for (int j = 0; j < 4; ++j)
#pragma unroll
      for (int r = 0; r < 4; ++r) {
        pf[j >> 1][4 * (j & 1) + r] = (bf16)fast_exp2(s[j][r]);
      }
    __builtin_amdgcn_s_setprio(1);
#pragma unroll
    for (int ss = 0; ss < 2; ++ss) {
      lacc = __builtin_amdgcn_mfma_f32_16x16x32_bf16(ones, pf[ss], lacc, 0, 0, 0);
#pragma unroll
      for (int j = 0; j < 4; ++j) {
        const bf16x8 vf = *reinterpret_cast<const bf16x8*>(
            shb + (ss ? ko1 : ko0) + (16384 + B * 8192 + j * 2048));
        oacc[j] = __builtin_amdgcn_mfma_f32_16x16x32_bf16(vf, pf[ss], oacc[j], 0, 0, 0);
      }
    }
    __builtin_amdgcn_s_setprio(0);
  };

  stage(Int<0>{});
  __syncthreads();
  for (int kt = 0; kt < 32; kt += 2) {
    stage(Int<1>{});
    compute(Int<0>{});
    __syncthreads();
    if (kt < 30) stage(Int<0>{});
    compute(Int<1>{});
    __syncthreads();
  }

  // epilogue: oacc[j][r] = O[q][d=16j+4fg+r]; l = lacc[0] (all slots equal)
  const int b = bh >> 3, h = bh & 7;
  const int q = q0 + fr;
  const float inv = 1.0f / lacc[0];
#pragma unroll
  for (int j = 0; j < 4; ++j) {
    bf16x4 o4;
#pragma unroll
    for (int r = 0; r < 4; ++r) o4[r] = (bf16)(oacc[j][r] * inv);
    *reinterpret_cast<bf16x4*>(&Ob[(b * 2048 + q) * 512 + h * 64 + 16 * j + 4 * fg]) = o4;
  }
}

// Y[m][n] = sum_k O[m][k]*W[n][k] + bias[n];  M=8192, N=512, K=512. fp32 out.
__global__ __launch_bounds__(256) void out_gemm(const bf16* __restrict__ O,
                                                const bf16* __restrict__ W,
                                                const float* __restrict__ bias,
                                                float* __restrict__ Y) {
  __shared__ __align__(16) bf16 Ash[2][64 * 32];
  __shared__ __align__(16) bf16 Bsh[2][64 * 32];
  const int t = threadIdx.x;
  const int lane = t & 63;
  const int w = t >> 6;
  const int fr = lane & 15, fg = lane >> 4;
  const int m0 = blockIdx.x * 64;
  const int n0 = blockIdx.y * 64;
  const int srow = t >> 2, sseg = t & 3;
  const bf16* gA = O + (m0 + srow) * 512 + sseg * 8;
  const bf16* gB = W + (n0 + srow) * 512 + sseg * 8;

  f32x4 acc[4] = {};
  gl2lds16(gA, &Ash[0][t * 8]);
  gl2lds16(gB, &Bsh[0][t * 8]);
  __syncthreads();
  int cur = 0;
  for (int kt = 0; kt < 16; ++kt) {
    if (kt < 15) {
      gl2lds16(gA + (kt + 1) * 32, &Ash[cur ^ 1][t * 8]);
      gl2lds16(gB + (kt + 1) * 32, &Bsh[cur ^ 1][t * 8]);
    }
    const bf16x8 a = *reinterpret_cast<const bf16x8*>(&Ash[cur][(16 * w + fr) * 32 + fg * 8]);
#pragma unroll
    for (int j = 0; j < 4; ++j) {
      const bf16x8 b = *reinterpret_cast<const bf16x8*>(&Bsh[cur][(16 * j + fr) * 32 + fg * 8]);
      acc[j] = __builtin_amdgcn_mfma_f32_16x16x32_bf16(a, b, acc[j], 0, 0, 0);
    }
    __syncthreads();
    cur ^= 1;
  }
  const int mbase = m0 + 16 * w + fg * 4;
#pragma unroll
  for (int j = 0; j < 4; ++j) {
    const int col = n0 + 16 * j + fr;
    const float bv = bias[col];
#pragma unroll
    for (int r = 0; r < 4; ++r) {
      Y[(mbase + r) * 512 + col] = acc[j][r] + bv;
    }
  }
}

extern "C" void kernel_launch(void* const* d_in, const int* in_sizes, int n_in,
                              void* d_out, int out_size, void* d_ws, size_t ws_size,
                              hipStream_t stream) {
  const float* x = (const float*)d_in[0];      // [4,2048,512]
  const float* w_qkv = (const float*)d_in[1];  // [1536,512]
  const float* w_out = (const float*)d_in[2];  // [512,512]
  const float* b_out = (const float*)d_in[3];  // [512]
  float* y = (float*)d_out;                    // [4,2048,512] fp32
  char* ws = (char*)d_ws;
  bf16* xb    = (bf16*)(ws);             // 8 MB
  bf16* wqkvb = (bf16*)(ws + 8388608);   // 1.5 MB
  bf16* woutb = (bf16*)(ws + 9961472);   // 0.5 MB
  bf16* Qb    = (bf16*)(ws + 10485760);  // 8 MB  [BH][N][64], prescaled
  bf16* Kb    = (bf16*)(ws + 18874368);  // 8 MB  [BH][N][64]
  bf16* Vt    = (bf16*)(ws + 27262976);  // 8 MB  [BH][64][N]
  bf16* Ob    = (bf16*)(ws + 35651584);  // 8 MB  [B][N][512]

  hipLaunchKernelGGL(cvt_f32_bf16, dim3(2048), dim3(256), 0, stream, x, xb, 4194304 / 4);
  hipLaunchKernelGGL(cvt_f32_bf16, dim3(768), dim3(256), 0, stream, w_qkv, wqkvb, 786432 / 4);
  hipLaunchKernelGGL(cvt_f32_bf16, dim3(256), dim3(256), 0, stream, w_out, woutb, 262144 / 4);
  hipLaunchKernelGGL(qkv_gemm, dim3(64, 12), dim3(256), 0, stream, xb, wqkvb, Qb, Kb, Vt);
  hipLaunchKernelGGL(attn_fwd, dim3(32, 32), dim3(256), 0, stream, Qb, Kb, Vt, Ob);
  hipLaunchKernelGGL(out_gemm, dim3(128, 8), dim3(256), 0, stream, Ob, woutb, b_out, y);
}

// Round 8
// 84.757 us; speedup vs baseline: 1.1498x; 1.0258x over previous
//
#include <hip/hip_runtime.h>
#include <hip/hip_bf16.h>
#include <stdint.h>

typedef __bf16 bf16;
typedef __bf16 bf16x8 __attribute__((ext_vector_type(8)));
typedef __bf16 bf16x4 __attribute__((ext_vector_type(4)));
typedef float f32x4 __attribute__((ext_vector_type(4)));

template <int V> struct Int { static constexpr int value = V; };

// async global->LDS, 16B per lane. LDS dest must be linear in lane order.
static __device__ __forceinline__ void gl2lds16(const void* g, void* l) {
  const __attribute__((address_space(1))) void* gp =
      reinterpret_cast<const __attribute__((address_space(1))) void*>(
          reinterpret_cast<uintptr_t>(g));
  __attribute__((address_space(3))) void* lp =
      reinterpret_cast<__attribute__((address_space(3))) void*>(
          static_cast<uint32_t>(reinterpret_cast<uintptr_t>(l)));
  __builtin_amdgcn_global_load_lds(gp, lp, 16, 0, 0);
}

// bare v_exp_f32 through the compiler intrinsic (hazard-safe, unlike inline asm).
static __device__ __forceinline__ float fast_exp2(float x) {
#if __has_builtin(__builtin_amdgcn_exp2f)
  return __builtin_amdgcn_exp2f(x);
#else
  return exp2f(x);
#endif
}

// One fused convert: x (4,194,304 f32) | w_qkv (786,432) | w_out (262,144) ->
// contiguous bf16 stream in ws (xb|wqkvb|woutb are adjacent).
__global__ __launch_bounds__(256) void cvt_all(const float* __restrict__ x,
                                               const float* __restrict__ wq,
                                               const float* __restrict__ wo,
                                               bf16* __restrict__ dst) {
  int i = blockIdx.x * 256 + threadIdx.x;
  const int stride = gridDim.x * 256;
  for (; i < 1310720; i += stride) {
    const float4 v = (i < 1048576) ? reinterpret_cast<const float4*>(x)[i]
                   : (i < 1245184) ? reinterpret_cast<const float4*>(wq)[i - 1048576]
                                   : reinterpret_cast<const float4*>(wo)[i - 1245184];
    bf16x4 o;
    o[0] = (bf16)v.x; o[1] = (bf16)v.y; o[2] = (bf16)v.z; o[3] = (bf16)v.w;
    reinterpret_cast<bf16x4*>(dst)[i] = o;
  }
}

// C[m][e] = sum_k X[m][k] * W[e][k];  M=8192, N=1536, K=512.  128x128 tile, BK=32.
// 4 waves, each owns 64x64 (4x4 frags of 16x16x32). Epilogue scatters Q/K/V^T.
__global__ __launch_bounds__(256) void qkv_gemm(const bf16* __restrict__ X,
                                                const bf16* __restrict__ W,
                                                bf16* __restrict__ Qb,
                                                bf16* __restrict__ Kb,
                                                bf16* __restrict__ Vt) {
  __shared__ __align__(16) bf16 AshX[8192];  // [2][128*32]
  __shared__ __align__(16) bf16 BshX[8192];
  const int t = threadIdx.x;
  const int lane = t & 63;
  const int w = t >> 6;
  const int fr = lane & 15, fg = lane >> 4;
  const int wr = w >> 1, wc = w & 1;
  const int m0 = blockIdx.x * 128;
  const int n0 = blockIdx.y * 128;
  // staging: chunk t -> row t>>2, seg t&3 -> LDS elem t*8; chunk t+256 -> +2048
  const int r0 = t >> 2, seg = t & 3;
  const bf16* pA0 = X + (m0 + r0) * 512 + seg * 8;
  const bf16* pA1 = X + (m0 + r0 + 64) * 512 + seg * 8;
  const bf16* pB0 = W + (n0 + r0) * 512 + seg * 8;
  const bf16* pB1 = W + (n0 + r0 + 64) * 512 + seg * 8;
  const bf16* ap = AshX + (wr * 64 + fr) * 32 + fg * 8;
  const bf16* bp = BshX + (wc * 64 + fr) * 32 + fg * 8;

  f32x4 acc[4][4] = {};

  auto stage = [&](auto Bt) {
    constexpr int B = decltype(Bt)::value;
    gl2lds16(pA0, (void*)(AshX + B * 4096 + t * 8));
    gl2lds16(pA1, (void*)(AshX + B * 4096 + 2048 + t * 8));
    gl2lds16(pB0, (void*)(BshX + B * 4096 + t * 8));
    gl2lds16(pB1, (void*)(BshX + B * 4096 + 2048 + t * 8));
    pA0 += 32; pA1 += 32; pB0 += 32; pB1 += 32;
  };
  auto step = [&](auto Bt) {
    constexpr int B = decltype(Bt)::value;
    bf16x8 a[4], b[4];
#pragma unroll
    for (int m = 0; m < 4; ++m) a[m] = *reinterpret_cast<const bf16x8*>(ap + B * 4096 + m * 512);
#pragma unroll
    for (int n = 0; n < 4; ++n) b[n] = *reinterpret_cast<const bf16x8*>(bp + B * 4096 + n * 512);
#pragma unroll
    for (int m = 0; m < 4; ++m)
#pragma unroll
      for (int n = 0; n < 4; ++n)
        acc[m][n] = __builtin_amdgcn_mfma_f32_16x16x32_bf16(a[m], b[n], acc[m][n], 0, 0, 0);
  };

  stage(Int<0>{});
  __syncthreads();
  for (int kt = 0; kt < 16; kt += 2) {
    stage(Int<1>{});
    step(Int<0>{});
    __syncthreads();
    if (kt < 14) stage(Int<0>{});
    step(Int<1>{});
    __syncthreads();
  }

  // epilogue. C/D: col = lane&15 -> e = n0+wc*64+16n+fr; row = m0+wr*64+16m+fg*4+r
  const int which = n0 >> 9;  // 0=Q 1=K 2=V (uniform per block)
#pragma unroll
  for (int n = 0; n < 4; ++n) {
    const int e = n0 + wc * 64 + 16 * n + fr;
    const int h = (e >> 6) & 7;
    const int d = e & 63;
#pragma unroll
    for (int m = 0; m < 4; ++m) {
      const int mbase = m0 + wr * 64 + 16 * m + fg * 4;
      if (which == 2) {
        bf16x4 pk;
#pragma unroll
        for (int r = 0; r < 4; ++r) pk[r] = (bf16)acc[m][n][r];
        const int b = mbase >> 11, tok = mbase & 2047;
        *reinterpret_cast<bf16x4*>(&Vt[((b * 8 + h) * 64 + d) * 2048 + tok]) = pk;
      } else {
        bf16* dst = (which == 0) ? Qb : Kb;
        const float sc = (which == 0) ? (0.125f * 1.44269504088896f) : 1.0f;
#pragma unroll
        for (int r = 0; r < 4; ++r) {
          const int row = mbase + r;
          const int b = row >> 11, tok = row & 2047;
          dst[((b * 8 + h) * 2048 + tok) * 64 + d] = (bf16)(acc[m][n][r] * sc);
        }
      }
    }
  }
}

// Flash attention, swapped-operand, no-max exp2 softmax, q=16 per wave.
// Q [BH][2048][64] (prescaled by 0.125*log2e), K [BH][2048][64], V^T [BH][64][2048].
// Block: 4 waves x 16 q-rows = 64 q. Grid (32 qtile, 32 bh): consecutive block ids
// share bh -> per-XCD L2 holds one head's K/V.
// K rows PERMUTED at staging so S^T lands in PV B-frag layout (see r3 header).
// 4-slot LDS pipeline (64KB), prefetch depth 2, counted vmcnt (never 0 in loop):
//   phase t: stage(tile t+2 -> slot (t+2)&3); vmcnt(8); s_barrier; compute(slot t&3).
//   Safety: slot (t+2)&3 was read at phase t-2; all waves passed barrier t-1.
// LDS arena: K slot s @ bytes s*8192, V slot s @ bytes 32768 + s*8192; XOR-swizzled.
__global__ __launch_bounds__(256, 2) void attn_fwd(const bf16* __restrict__ Qb,
                                                   const bf16* __restrict__ Kb,
                                                   const bf16* __restrict__ Vt,
                                                   bf16* __restrict__ Ob) {
  __shared__ __align__(16) bf16 sh[32768];
  const int t = threadIdx.x;
  const int lane = t & 63;
  const int w = t >> 6;
  const int fr = lane & 15, fg = lane >> 4;
  const int bh = blockIdx.y;
  const int q0 = blockIdx.x * 64 + 16 * w;

  // Q fragment (B-operand): col=q=q0+fr, k = 8*fg + i
  const bf16* Qrow = Qb + (bh * 2048 + q0 + fr) * 64;
  const bf16x8 qf0 = *reinterpret_cast<const bf16x8*>(Qrow + fg * 8);
  const bf16x8 qf1 = *reinterpret_cast<const bf16x8*>(Qrow + 32 + fg * 8);

  bf16x8 ones;
#pragma unroll
  for (int i = 0; i < 8; ++i) ones[i] = (bf16)1.0f;

  // staging: chunk c: LDS row=c>>3, seg=c&7; src seg ^= (dstrow&7); K row-permuted.
  const int c0row = t >> 3, cseg = t & 7;
  const int c1row = c0row + 32;
  const int s0 = (cseg ^ (c0row & 7)) * 8;
  const int s1 = (cseg ^ (c1row & 7)) * 8;
  const int kp0 = 32 * ((c0row >> 4) >> 1) + 8 * ((c0row & 15) >> 2) +
                  4 * ((c0row >> 4) & 1) + (c0row & 3);
  const int kp1 = 32 * ((c1row >> 4) >> 1) + 8 * ((c1row & 15) >> 2) +
                  4 * ((c1row >> 4) & 1) + (c1row & 3);
  const bf16* pK0 = Kb + bh * 131072 + kp0 * 64 + s0;
  const bf16* pK1 = Kb + bh * 131072 + kp1 * 64 + s1;
  const bf16* pV0 = Vt + bh * 131072 + c0row * 2048 + s0;
  const bf16* pV1 = Vt + bh * 131072 + c1row * 2048 + s1;

  // LDS read byte offsets (2 VGPRs; everything else is an immediate)
  const int swz = (fr & 7) << 4;
  const int ko0 = fr * 128 + ((fg * 16) ^ swz);
  const int ko1 = fr * 128 + ((64 + fg * 16) ^ swz);
  const char* shb = reinterpret_cast<const char*>(sh);

  f32x4 oacc[4] = {};
  f32x4 lacc = {};
  const f32x4 fzero = {0.f, 0.f, 0.f, 0.f};

  auto stage = [&](auto St) {
    constexpr int S = decltype(St)::value;
    gl2lds16(pK0, (void*)(sh + S * 4096 + t * 8));
    gl2lds16(pK1, (void*)(sh + S * 4096 + 2048 + t * 8));
    gl2lds16(pV0, (void*)(sh + 16384 + S * 4096 + t * 8));
    gl2lds16(pV1, (void*)(sh + 16384 + S * 4096 + 2048 + t * 8));
    pK0 += 4096; pK1 += 4096; pV0 += 64; pV1 += 64;
  };

  auto compute = [&](auto St) {
    constexpr int S = decltype(St)::value;
    f32x4 s[4];
#pragma unroll
    for (int j = 0; j < 4; ++j) {
      const bf16x8 kf0 = *reinterpret_cast<const bf16x8*>(shb + ko0 + (S * 8192 + j * 2048));
      s[j] = __builtin_amdgcn_mfma_f32_16x16x32_bf16(kf0, qf0, fzero, 0, 0, 0);
      const bf16x8 kf1 = *reinterpret_cast<const bf16x8*>(shb + ko1 + (S * 8192 + j * 2048));
      s[j] = __builtin_amdgcn_mfma_f32_16x16x32_bf16(kf1, qf1, s[j], 0, 0, 0);
    }
    bf16x8 pf[2];
#pragma unroll
    for (int j = 0; j < 4; ++j)
#pragma unroll
      for (int r = 0; r < 4; ++r) {
        pf[j >> 1][4 * (j & 1) + r] = (bf16)fast_exp2(s[j][r]);
      }
    __builtin_amdgcn_s_setprio(1);
#pragma unroll
    for (int ss = 0; ss < 2; ++ss) {
      lacc = __builtin_amdgcn_mfma_f32_16x16x32_bf16(ones, pf[ss], lacc, 0, 0, 0);
#pragma unroll
      for (int j = 0; j < 4; ++j) {
        const bf16x8 vf = *reinterpret_cast<const bf16x8*>(
            shb + (ss ? ko1 : ko0) + (32768 + S * 8192 + j * 2048));
        oacc[j] = __builtin_amdgcn_mfma_f32_16x16x32_bf16(vf, pf[ss], oacc[j], 0, 0, 0);
      }
    }
    __builtin_amdgcn_s_setprio(0);
  };

  auto phase = [&](auto ReadS, auto StageS, auto Vm) {
    constexpr int ST = decltype(StageS)::value;
    constexpr int VM = decltype(Vm)::value;
    if constexpr (ST >= 0) stage(Int<ST>{});
    if constexpr (VM == 8) asm volatile("s_waitcnt vmcnt(8)" ::: "memory");
    else if constexpr (VM == 4) asm volatile("s_waitcnt vmcnt(4)" ::: "memory");
    else asm volatile("s_waitcnt vmcnt(0)" ::: "memory");
    __builtin_amdgcn_s_barrier();
    __builtin_amdgcn_sched_barrier(0);
    compute(ReadS);
  };

  // prologue: tiles 0,1 into slots 0,1
  stage(Int<0>{});
  stage(Int<1>{});
  // 32 tiles total: 28 pipelined phases + 4 tail phases
  for (int kt = 0; kt < 28; kt += 4) {
    phase(Int<0>{}, Int<2>{}, Int<8>{});
    phase(Int<1>{}, Int<3>{}, Int<8>{});
    phase(Int<2>{}, Int<0>{}, Int<8>{});
    phase(Int<3>{}, Int<1>{}, Int<8>{});
  }
  phase(Int<0>{}, Int<2>{}, Int<8>{});   // t=28, stage tile 30
  phase(Int<1>{}, Int<3>{}, Int<8>{});   // t=29, stage tile 31
  phase(Int<2>{}, Int<-1>{}, Int<4>{});  // t=30
  phase(Int<3>{}, Int<-1>{}, Int<0>{});  // t=31

  // epilogue: oacc[j][r] = O[q][d=16j+4fg+r]; l = lacc[0] (all slots equal)
  const int b = bh >> 3, h = bh & 7;
  const int q = q0 + fr;
  const float inv = 1.0f / lacc[0];
#pragma unroll
  for (int j = 0; j < 4; ++j) {
    bf16x4 o4;
#pragma unroll
    for (int r = 0; r < 4; ++r) o4[r] = (bf16)(oacc[j][r] * inv);
    *reinterpret_cast<bf16x4*>(&Ob[(b * 2048 + q) * 512 + h * 64 + 16 * j + 4 * fg]) = o4;
  }
}

// Y[m][n] = sum_k O[m][k]*W[n][k] + bias[n];  M=8192, N=512, K=512. fp32 out.
__global__ __launch_bounds__(256) void out_gemm(const bf16* __restrict__ O,
                                                const bf16* __restrict__ W,
                                                const float* __restrict__ bias,
                                                float* __restrict__ Y) {
  __shared__ __align__(16) bf16 Ash[2][64 * 32];
  __shared__ __align__(16) bf16 Bsh[2][64 * 32];
  const int t = threadIdx.x;
  const int lane = t & 63;
  const int w = t >> 6;
  const int fr = lane & 15, fg = lane >> 4;
  const int m0 = blockIdx.x * 64;
  const int n0 = blockIdx.y * 64;
  const int srow = t >> 2, sseg = t & 3;
  const bf16* gA = O + (m0 + srow) * 512 + sseg * 8;
  const bf16* gB = W + (n0 + srow) * 512 + sseg * 8;

  f32x4 acc[4] = {};
  gl2lds16(gA, &Ash[0][t * 8]);
  gl2lds16(gB, &Bsh[0][t * 8]);
  __syncthreads();
  int cur = 0;
  for (int kt = 0; kt < 16; ++kt) {
    if (kt < 15) {
      gl2lds16(gA + (kt + 1) * 32, &Ash[cur ^ 1][t * 8]);
      gl2lds16(gB + (kt + 1) * 32, &Bsh[cur ^ 1][t * 8]);
    }
    const bf16x8 a = *reinterpret_cast<const bf16x8*>(&Ash[cur][(16 * w + fr) * 32 + fg * 8]);
#pragma unroll
    for (int j = 0; j < 4; ++j) {
      const bf16x8 b = *reinterpret_cast<const bf16x8*>(&Bsh[cur][(16 * j + fr) * 32 + fg * 8]);
      acc[j] = __builtin_amdgcn_mfma_f32_16x16x32_bf16(a, b, acc[j], 0, 0, 0);
    }
    __syncthreads();
    cur ^= 1;
  }
  const int mbase = m0 + 16 * w + fg * 4;
#pragma unroll
  for (int j = 0; j < 4; ++j) {
    const int col = n0 + 16 * j + fr;
    const float bv = bias[col];
#pragma unroll
    for (int r = 0; r < 4; ++r) {
      Y[(mbase + r) * 512 + col] = acc[j][r] + bv;
    }
  }
}

extern "C" void kernel_launch(void* const* d_in, const int* in_sizes, int n_in,
                              void* d_out, int out_size, void* d_ws, size_t ws_size,
                              hipStream_t stream) {
  const float* x = (const float*)d_in[0];      // [4,2048,512]
  const float* w_qkv = (const float*)d_in[1];  // [1536,512]
  const float* w_out = (const float*)d_in[2];  // [512,512]
  const float* b_out = (const float*)d_in[3];  // [512]
  float* y = (float*)d_out;                    // [4,2048,512] fp32
  char* ws = (char*)d_ws;
  bf16* xb    = (bf16*)(ws);             // 8 MB
  bf16* wqkvb = (bf16*)(ws + 8388608);   // 1.5 MB
  bf16* woutb = (bf16*)(ws + 9961472);   // 0.5 MB
  bf16* Qb    = (bf16*)(ws + 10485760);  // 8 MB  [BH][N][64], prescaled
  bf16* Kb    = (bf16*)(ws + 18874368);  // 8 MB  [BH][N][64]
  bf16* Vt    = (bf16*)(ws + 27262976);  // 8 MB  [BH][64][N]
  bf16* Ob    = (bf16*)(ws + 35651584);  // 8 MB  [B][N][512]

  hipLaunchKernelGGL(cvt_all, dim3(5120), dim3(256), 0, stream, x, w_qkv, w_out, xb);
  hipLaunchKernelGGL(qkv_gemm, dim3(64, 12), dim3(256), 0, stream, xb, wqkvb, Qb, Kb, Vt);
  hipLaunchKernelGGL(attn_fwd, dim3(32, 32), dim3(256), 0, stream, Qb, Kb, Vt, Ob);
  hipLaunchKernelGGL(out_gemm, dim3(128, 8), dim3(256), 0, stream, Ob, woutb, b_out, y);
}

// Round 9
// 82.289 us; speedup vs baseline: 1.1843x; 1.0300x over previous
//
#include <hip/hip_runtime.h>
#include <hip/hip_bf16.h>
#include <stdint.h>

typedef __bf16 bf16;
typedef __bf16 bf16x8 __attribute__((ext_vector_type(8)));
typedef __bf16 bf16x4 __attribute__((ext_vector_type(4)));
typedef float f32x4 __attribute__((ext_vector_type(4)));

template <int V> struct Int { static constexpr int value = V; };

// async global->LDS, 16B per lane. LDS dest must be linear in lane order.
static __device__ __forceinline__ void gl2lds16(const void* g, void* l) {
  const __attribute__((address_space(1))) void* gp =
      reinterpret_cast<const __attribute__((address_space(1))) void*>(
          reinterpret_cast<uintptr_t>(g));
  __attribute__((address_space(3))) void* lp =
      reinterpret_cast<__attribute__((address_space(3))) void*>(
          static_cast<uint32_t>(reinterpret_cast<uintptr_t>(l)));
  __builtin_amdgcn_global_load_lds(gp, lp, 16, 0, 0);
}

// bare v_exp_f32 through the compiler intrinsic (hazard-safe, unlike inline asm).
static __device__ __forceinline__ float fast_exp2(float x) {
#if __has_builtin(__builtin_amdgcn_exp2f)
  return __builtin_amdgcn_exp2f(x);
#else
  return exp2f(x);
#endif
}

// One fused convert: x (4,194,304 f32) | w_qkv (786,432) | w_out (262,144) ->
// contiguous bf16 stream in ws (xb|wqkvb|woutb are adjacent).
__global__ __launch_bounds__(256) void cvt_all(const float* __restrict__ x,
                                               const float* __restrict__ wq,
                                               const float* __restrict__ wo,
                                               bf16* __restrict__ dst) {
  int i = blockIdx.x * 256 + threadIdx.x;
  const int stride = gridDim.x * 256;
  for (; i < 1310720; i += stride) {
    const float4 v = (i < 1048576) ? reinterpret_cast<const float4*>(x)[i]
                   : (i < 1245184) ? reinterpret_cast<const float4*>(wq)[i - 1048576]
                                   : reinterpret_cast<const float4*>(wo)[i - 1245184];
    bf16x4 o;
    o[0] = (bf16)v.x; o[1] = (bf16)v.y; o[2] = (bf16)v.z; o[3] = (bf16)v.w;
    reinterpret_cast<bf16x4*>(dst)[i] = o;
  }
}

// C[m][e] = sum_k X[m][k] * W[e][k];  M=8192, N=1536, K=512.  128x128 tile, BK=32.
// 4 waves, each owns 64x64 (4x4 frags of 16x16x32). Epilogue scatters Q/K/V^T.
__global__ __launch_bounds__(256) void qkv_gemm(const bf16* __restrict__ X,
                                                const bf16* __restrict__ W,
                                                bf16* __restrict__ Qb,
                                                bf16* __restrict__ Kb,
                                                bf16* __restrict__ Vt) {
  __shared__ __align__(16) bf16 AshX[8192];  // [2][128*32]
  __shared__ __align__(16) bf16 BshX[8192];
  const int t = threadIdx.x;
  const int lane = t & 63;
  const int w = t >> 6;
  const int fr = lane & 15, fg = lane >> 4;
  const int wr = w >> 1, wc = w & 1;
  const int m0 = blockIdx.x * 128;
  const int n0 = blockIdx.y * 128;
  // staging: chunk t -> row t>>2, seg t&3 -> LDS elem t*8; chunk t+256 -> +2048
  const int r0 = t >> 2, seg = t & 3;
  const bf16* pA0 = X + (m0 + r0) * 512 + seg * 8;
  const bf16* pA1 = X + (m0 + r0 + 64) * 512 + seg * 8;
  const bf16* pB0 = W + (n0 + r0) * 512 + seg * 8;
  const bf16* pB1 = W + (n0 + r0 + 64) * 512 + seg * 8;
  const bf16* ap = AshX + (wr * 64 + fr) * 32 + fg * 8;
  const bf16* bp = BshX + (wc * 64 + fr) * 32 + fg * 8;

  f32x4 acc[4][4] = {};

  auto stage = [&](auto Bt) {
    constexpr int B = decltype(Bt)::value;
    gl2lds16(pA0, (void*)(AshX + B * 4096 + t * 8));
    gl2lds16(pA1, (void*)(AshX + B * 4096 + 2048 + t * 8));
    gl2lds16(pB0, (void*)(BshX + B * 4096 + t * 8));
    gl2lds16(pB1, (void*)(BshX + B * 4096 + 2048 + t * 8));
    pA0 += 32; pA1 += 32; pB0 += 32; pB1 += 32;
  };
  auto step = [&](auto Bt) {
    constexpr int B = decltype(Bt)::value;
    bf16x8 a[4], b[4];
#pragma unroll
    for (int m = 0; m < 4; ++m) a[m] = *reinterpret_cast<const bf16x8*>(ap + B * 4096 + m * 512);
#pragma unroll
    for (int n = 0; n < 4; ++n) b[n] = *reinterpret_cast<const bf16x8*>(bp + B * 4096 + n * 512);
#pragma unroll
    for (int m = 0; m < 4; ++m)
#pragma unroll
      for (int n = 0; n < 4; ++n)
        acc[m][n] = __builtin_amdgcn_mfma_f32_16x16x32_bf16(a[m], b[n], acc[m][n], 0, 0, 0);
  };

  stage(Int<0>{});
  __syncthreads();
  for (int kt = 0; kt < 16; kt += 2) {
    stage(Int<1>{});
    step(Int<0>{});
    __syncthreads();
    if (kt < 14) stage(Int<0>{});
    step(Int<1>{});
    __syncthreads();
  }

  // epilogue. C/D: col = lane&15 -> e = n0+wc*64+16n+fr; row = m0+wr*64+16m+fg*4+r
  const int which = n0 >> 9;  // 0=Q 1=K 2=V (uniform per block)
#pragma unroll
  for (int n = 0; n < 4; ++n) {
    const int e = n0 + wc * 64 + 16 * n + fr;
    const int h = (e >> 6) & 7;
    const int d = e & 63;
#pragma unroll
    for (int m = 0; m < 4; ++m) {
      const int mbase = m0 + wr * 64 + 16 * m + fg * 4;
      if (which == 2) {
        bf16x4 pk;
#pragma unroll
        for (int r = 0; r < 4; ++r) pk[r] = (bf16)acc[m][n][r];
        const int b = mbase >> 11, tok = mbase & 2047;
        *reinterpret_cast<bf16x4*>(&Vt[((b * 8 + h) * 64 + d) * 2048 + tok]) = pk;
      } else {
        bf16* dst = (which == 0) ? Qb : Kb;
        const float sc = (which == 0) ? (0.125f * 1.44269504088896f) : 1.0f;
#pragma unroll
        for (int r = 0; r < 4; ++r) {
          const int row = mbase + r;
          const int b = row >> 11, tok = row & 2047;
          dst[((b * 8 + h) * 2048 + tok) * 64 + d] = (bf16)(acc[m][n][r] * sc);
        }
      }
    }
  }
}

// Flash attention, swapped-operand, no-max exp2 softmax, q=16 per wave.
// Q [BH][2048][64] (prescaled by 0.125*log2e), K [BH][2048][64], V^T [BH][64][2048].
// Block: 4 waves x 16 q-rows = 64 q. Grid (32 bh, 32 qtile): all qtiles of head bh
// have block id == bh (mod 8) -> one XCD per head; per-XCD K/V working set 2MB < L2.
// K rows PERMUTED at staging so S^T lands in PV B-frag layout (see r3 header).
// 4-slot LDS pipeline (64KB), prefetch depth 2, counted vmcnt (never 0 in loop):
//   phase t: stage(tile t+2 -> slot (t+2)&3); vmcnt(8); s_barrier; compute(slot t&3).
//   Safety: slot (t+2)&3 was read at phase t-2; all waves passed barrier t-1.
// LDS arena: K slot s @ bytes s*8192, V slot s @ bytes 32768 + s*8192; XOR-swizzled.
__global__ __launch_bounds__(256, 2) void attn_fwd(const bf16* __restrict__ Qb,
                                                   const bf16* __restrict__ Kb,
                                                   const bf16* __restrict__ Vt,
                                                   bf16* __restrict__ Ob) {
  __shared__ __align__(16) bf16 sh[32768];
  const int t = threadIdx.x;
  const int lane = t & 63;
  const int w = t >> 6;
  const int fr = lane & 15, fg = lane >> 4;
  const int bh = blockIdx.x;
  const int q0 = blockIdx.y * 64 + 16 * w;

  // Q fragment (B-operand): col=q=q0+fr, k = 8*fg + i
  const bf16* Qrow = Qb + (bh * 2048 + q0 + fr) * 64;
  const bf16x8 qf0 = *reinterpret_cast<const bf16x8*>(Qrow + fg * 8);
  const bf16x8 qf1 = *reinterpret_cast<const bf16x8*>(Qrow + 32 + fg * 8);

  bf16x8 ones;
#pragma unroll
  for (int i = 0; i < 8; ++i) ones[i] = (bf16)1.0f;

  // staging: chunk c: LDS row=c>>3, seg=c&7; src seg ^= (dstrow&7); K row-permuted.
  const int c0row = t >> 3, cseg = t & 7;
  const int c1row = c0row + 32;
  const int s0 = (cseg ^ (c0row & 7)) * 8;
  const int s1 = (cseg ^ (c1row & 7)) * 8;
  const int kp0 = 32 * ((c0row >> 4) >> 1) + 8 * ((c0row & 15) >> 2) +
                  4 * ((c0row >> 4) & 1) + (c0row & 3);
  const int kp1 = 32 * ((c1row >> 4) >> 1) + 8 * ((c1row & 15) >> 2) +
                  4 * ((c1row >> 4) & 1) + (c1row & 3);
  const bf16* pK0 = Kb + bh * 131072 + kp0 * 64 + s0;
  const bf16* pK1 = Kb + bh * 131072 + kp1 * 64 + s1;
  const bf16* pV0 = Vt + bh * 131072 + c0row * 2048 + s0;
  const bf16* pV1 = Vt + bh * 131072 + c1row * 2048 + s1;

  // LDS read byte offsets (2 VGPRs; everything else is an immediate)
  const int swz = (fr & 7) << 4;
  const int ko0 = fr * 128 + ((fg * 16) ^ swz);
  const int ko1 = fr * 128 + ((64 + fg * 16) ^ swz);
  const char* shb = reinterpret_cast<const char*>(sh);

  f32x4 oacc[4] = {};
  f32x4 lacc = {};
  const f32x4 fzero = {0.f, 0.f, 0.f, 0.f};

  auto stage = [&](auto St) {
    constexpr int S = decltype(St)::value;
    gl2lds16(pK0, (void*)(sh + S * 4096 + t * 8));
    gl2lds16(pK1, (void*)(sh + S * 4096 + 2048 + t * 8));
    gl2lds16(pV0, (void*)(sh + 16384 + S * 4096 + t * 8));
    gl2lds16(pV1, (void*)(sh + 16384 + S * 4096 + 2048 + t * 8));
    pK0 += 4096; pK1 += 4096; pV0 += 64; pV1 += 64;
  };

  auto compute = [&](auto St) {
    constexpr int S = decltype(St)::value;
    f32x4 s[4];
#pragma unroll
    for (int j = 0; j < 4; ++j) {
      const bf16x8 kf0 = *reinterpret_cast<const bf16x8*>(shb + ko0 + (S * 8192 + j * 2048));
      s[j] = __builtin_amdgcn_mfma_f32_16x16x32_bf16(kf0, qf0, fzero, 0, 0, 0);
      const bf16x8 kf1 = *reinterpret_cast<const bf16x8*>(shb + ko1 + (S * 8192 + j * 2048));
      s[j] = __builtin_amdgcn_mfma_f32_16x16x32_bf16(kf1, qf1, s[j], 0, 0, 0);
    }
    bf16x8 pf[2];
#pragma unroll
    for (int j = 0; j < 4; ++j)
#pragma unroll
      for (int r = 0; r < 4; ++r) {
        pf[j >> 1][4 * (j & 1) + r] = (bf16)fast_exp2(s[j][r]);
      }
    __builtin_amdgcn_s_setprio(1);
#pragma unroll
    for (int ss = 0; ss < 2; ++ss) {
      lacc = __builtin_amdgcn_mfma_f32_16x16x32_bf16(ones, pf[ss], lacc, 0, 0, 0);
#pragma unroll
      for (int j = 0; j < 4; ++j) {
        const bf16x8 vf = *reinterpret_cast<const bf16x8*>(
            shb + (ss ? ko1 : ko0) + (32768 + S * 8192 + j * 2048));
        oacc[j] = __builtin_amdgcn_mfma_f32_16x16x32_bf16(vf, pf[ss], oacc[j], 0, 0, 0);
      }
    }
    __builtin_amdgcn_s_setprio(0);
  };

  auto phase = [&](auto ReadS, auto StageS, auto Vm) {
    constexpr int ST = decltype(StageS)::value;
    constexpr int VM = decltype(Vm)::value;
    if constexpr (ST >= 0) stage(Int<ST>{});
    if constexpr (VM == 8) asm volatile("s_waitcnt vmcnt(8)" ::: "memory");
    else if constexpr (VM == 4) asm volatile("s_waitcnt vmcnt(4)" ::: "memory");
    else asm volatile("s_waitcnt vmcnt(0)" ::: "memory");
    __builtin_amdgcn_s_barrier();
    __builtin_amdgcn_sched_barrier(0);
    compute(ReadS);
  };

  // prologue: tiles 0,1 into slots 0,1
  stage(Int<0>{});
  stage(Int<1>{});
  // 32 tiles total: 28 pipelined phases + 4 tail phases
  for (int kt = 0; kt < 28; kt += 4) {
    phase(Int<0>{}, Int<2>{}, Int<8>{});
    phase(Int<1>{}, Int<3>{}, Int<8>{});
    phase(Int<2>{}, Int<0>{}, Int<8>{});
    phase(Int<3>{}, Int<1>{}, Int<8>{});
  }
  phase(Int<0>{}, Int<2>{}, Int<8>{});   // t=28, stage tile 30
  phase(Int<1>{}, Int<3>{}, Int<8>{});   // t=29, stage tile 31
  phase(Int<2>{}, Int<-1>{}, Int<4>{});  // t=30
  phase(Int<3>{}, Int<-1>{}, Int<0>{});  // t=31

  // epilogue: oacc[j][r] = O[q][d=16j+4fg+r]; l = lacc[0] (all slots equal)
  const int b = bh >> 3, h = bh & 7;
  const int q = q0 + fr;
  const float inv = 1.0f / lacc[0];
#pragma unroll
  for (int j = 0; j < 4; ++j) {
    bf16x4 o4;
#pragma unroll
    for (int r = 0; r < 4; ++r) o4[r] = (bf16)(oacc[j][r] * inv);
    *reinterpret_cast<bf16x4*>(&Ob[(b * 2048 + q) * 512 + h * 64 + 16 * j + 4 * fg]) = o4;
  }
}

// Y[m][n] = sum_k O[m][k]*W[n][k] + bias[n];  M=8192, N=512, K=512. fp32 out.
__global__ __launch_bounds__(256) void out_gemm(const bf16* __restrict__ O,
                                                const bf16* __restrict__ W,
                                                const float* __restrict__ bias,
                                                float* __restrict__ Y) {
  __shared__ __align__(16) bf16 Ash[2][64 * 32];
  __shared__ __align__(16) bf16 Bsh[2][64 * 32];
  const int t = threadIdx.x;
  const int lane = t & 63;
  const int w = t >> 6;
  const int fr = lane & 15, fg = lane >> 4;
  const int m0 = blockIdx.x * 64;
  const int n0 = blockIdx.y * 64;
  const int srow = t >> 2, sseg = t & 3;
  const bf16* gA = O + (m0 + srow) * 512 + sseg * 8;
  const bf16* gB = W + (n0 + srow) * 512 + sseg * 8;

  f32x4 acc[4] = {};
  gl2lds16(gA, &Ash[0][t * 8]);
  gl2lds16(gB, &Bsh[0][t * 8]);
  __syncthreads();
  int cur = 0;
  for (int kt = 0; kt < 16; ++kt) {
    if (kt < 15) {
      gl2lds16(gA + (kt + 1) * 32, &Ash[cur ^ 1][t * 8]);
      gl2lds16(gB + (kt + 1) * 32, &Bsh[cur ^ 1][t * 8]);
    }
    const bf16x8 a = *reinterpret_cast<const bf16x8*>(&Ash[cur][(16 * w + fr) * 32 + fg * 8]);
#pragma unroll
    for (int j = 0; j < 4; ++j) {
      const bf16x8 b = *reinterpret_cast<const bf16x8*>(&Bsh[cur][(16 * j + fr) * 32 + fg * 8]);
      acc[j] = __builtin_amdgcn_mfma_f32_16x16x32_bf16(a, b, acc[j], 0, 0, 0);
    }
    __syncthreads();
    cur ^= 1;
  }
  const int mbase = m0 + 16 * w + fg * 4;
#pragma unroll
  for (int j = 0; j < 4; ++j) {
    const int col = n0 + 16 * j + fr;
    const float bv = bias[col];
#pragma unroll
    for (int r = 0; r < 4; ++r) {
      Y[(mbase + r) * 512 + col] = acc[j][r] + bv;
    }
  }
}

extern "C" void kernel_launch(void* const* d_in, const int* in_sizes, int n_in,
                              void* d_out, int out_size, void* d_ws, size_t ws_size,
                              hipStream_t stream) {
  const float* x = (const float*)d_in[0];      // [4,2048,512]
  const float* w_qkv = (const float*)d_in[1];  // [1536,512]
  const float* w_out = (const float*)d_in[2];  // [512,512]
  const float* b_out = (const float*)d_in[3];  // [512]
  float* y = (float*)d_out;                    // [4,2048,512] fp32
  char* ws = (char*)d_ws;
  bf16* xb    = (bf16*)(ws);             // 8 MB
  bf16* wqkvb = (bf16*)(ws + 8388608);   // 1.5 MB
  bf16* woutb = (bf16*)(ws + 9961472);   // 0.5 MB
  bf16* Qb    = (bf16*)(ws + 10485760);  // 8 MB  [BH][N][64], prescaled
  bf16* Kb    = (bf16*)(ws + 18874368);  // 8 MB  [BH][N][64]
  bf16* Vt    = (bf16*)(ws + 27262976);  // 8 MB  [BH][64][N]
  bf16* Ob    = (bf16*)(ws + 35651584);  // 8 MB  [B][N][512]

  hipLaunchKernelGGL(cvt_all, dim3(5120), dim3(256), 0, stream, x, w_qkv, w_out, xb);
  hipLaunchKernelGGL(qkv_gemm, dim3(64, 12), dim3(256), 0, stream, xb, wqkvb, Qb, Kb, Vt);
  hipLaunchKernelGGL(attn_fwd, dim3(32, 32), dim3(256), 0, stream, Qb, Kb, Vt, Ob);
  hipLaunchKernelGGL(out_gemm, dim3(128, 8), dim3(256), 0, stream, Ob, woutb, b_out, y);
}